// Round 7
// baseline (39.936 us; speedup 1.0000x reference)
//
#include <hip/hip_runtime.h>
#include <math.h>

#define BB 2048
#define DD 512
#define NS 7
#define KK 1024   // 2*DD concatenated GEMM K
#define BM 128
#define BN 128
#define BK 64
#define NT (KK / BK)  // 16 K-steps

typedef __attribute__((ext_vector_type(8))) short short8;
typedef __attribute__((ext_vector_type(4))) float floatx4;

typedef const __attribute__((address_space(1))) void gv_t;
typedef __attribute__((address_space(3))) void lv_t;
__device__ __forceinline__ void gl2lds16(const void* g, void* l) {
  __builtin_amdgcn_global_load_lds((gv_t*)g, (lv_t*)l, 16, 0, 0);
}

__device__ __forceinline__ unsigned short f2bf(float f) {
  unsigned int u = __float_as_uint(f);
  u += 0x7FFFu + ((u >> 16) & 1u);  // RNE
  return (unsigned short)(u >> 16);
}
__device__ __forceinline__ float bf2f(unsigned short u) {
  return __uint_as_float(((unsigned)u) << 16);
}

// monotone float<->uint key for atomicMax over signed floats
__device__ __forceinline__ unsigned fkey(float f) {
  unsigned u = __float_as_uint(f);
  return (u & 0x80000000u) ? ~u : (u | 0x80000000u);
}
__device__ __forceinline__ float funkey(unsigned k) {
  unsigned u = (k & 0x80000000u) ? (k ^ 0x80000000u) : ~k;
  return __uint_as_float(u);
}

// chunk-XOR swizzle of the K index within each 64-col group, keyed by row&7.
// Producer (prep) writes swizzled; GEMM's linear global_load_lds staging then
// lands a swizzled LDS tile whose ds_read_b128 frag reads are bank-balanced.
__device__ __forceinline__ int swz(int row, int c) {
  return (c & ~0x38) | ((((c >> 3) ^ row) & 7) << 3);
}

__device__ __forceinline__ float wave_reduce_sum(float v) {
#pragma unroll
  for (int off = 32; off > 0; off >>= 1) v += __shfl_down(v, off, 64);
  return v;
}
__device__ __forceinline__ float wave_reduce_max(float v) {
#pragma unroll
  for (int off = 32; off > 0; off >>= 1) v = fmaxf(v, __shfl_down(v, off, 64));
  return v;
}
__device__ __forceinline__ float block_reduce_sum256(float v, float* sbuf) {
  v = wave_reduce_sum(v);
  if ((threadIdx.x & 63) == 0) sbuf[threadIdx.x >> 6] = v;
  __syncthreads();
  float r = sbuf[0] + sbuf[1] + sbuf[2] + sbuf[3];
  __syncthreads();
  return r;
}
__device__ __forceinline__ float block_reduce_max256(float v, float* sbuf) {
  v = wave_reduce_max(v);
  if ((threadIdx.x & 63) == 0) sbuf[threadIdx.x >> 6] = v;
  __syncthreads();
  float r = fmaxf(fmaxf(sbuf[0], sbuf[1]), fmaxf(sbuf[2], sbuf[3]));
  __syncthreads();
  return r;
}

// ---------------------------------------------------------------------------
// Kernel 1 (merged prep): 16B/lane float4, 2 rows per block.
// Blocks [0,1024): query rows 2b,2b+1.  Blocks [1024,2048): target rows.
// Group g = tid>>7 owns one row with 128 threads (2 waves).
__global__ __launch_bounds__(256) void prep(
    const float* __restrict__ qmean, const float* __restrict__ qls,
    const float* __restrict__ tmean, const float* __restrict__ tls,
    const float* __restrict__ eps,
    unsigned short* __restrict__ Acat, unsigned short* __restrict__ Bcat,
    float* __restrict__ qterm, unsigned* __restrict__ Mkey) {
  __shared__ float sbuf[8];  // [0..3]: reduce round 0, [4..7]: round 1
  const int b = blockIdx.x, tid = threadIdx.x;
  const int g = tid >> 7, lid = tid & 127, wv = (tid >> 6) & 1;
  const int c0 = 4 * lid;
  if (b < BB / 2) {
    const int q = 2 * b + g;
    float4 x = ((const float4*)(qmean + (size_t)q * DD))[lid];
    float4 l = ((const float4*)(qls + (size_t)q * DD))[lid];
    float ss = x.x * x.x + x.y * x.y + x.z * x.z + x.w * x.w;
    ss = wave_reduce_sum(ss);
    if ((tid & 63) == 0) sbuf[(g << 1) | wv] = ss;
    __syncthreads();
    ss = sbuf[g << 1] + sbuf[(g << 1) | 1];
    float inv = 1.0f / fmaxf(sqrtf(ss), 1e-12f);
    float w0 = expf(-l.x), w1 = expf(-l.y), w2 = expf(-l.z), w3 = expf(-l.w);
    float n0 = x.x * inv, n1 = x.y * inv, n2 = x.z * inv, n3 = x.w * inv;
    unsigned short* arow = Acat + (size_t)q * KK;
    ushort4 wp, np;
    wp.x = f2bf(w0); wp.y = f2bf(w1); wp.z = f2bf(w2); wp.w = f2bf(w3);
    np.x = f2bf(-2.0f * n0 * w0); np.y = f2bf(-2.0f * n1 * w1);
    np.z = f2bf(-2.0f * n2 * w2); np.w = f2bf(-2.0f * n3 * w3);
    *(ushort4*)&arow[swz(q, c0)]      = wp;
    *(ushort4*)&arow[swz(q, DD + c0)] = np;
    float qt = n0 * n0 * w0 + n1 * n1 * w1 + n2 * n2 * w2 + n3 * n3 * w3;
    qt = wave_reduce_sum(qt);
    if ((tid & 63) == 0) sbuf[4 + ((g << 1) | wv)] = qt;
    __syncthreads();
    if (lid == 0) qterm[q] = sbuf[4 + (g << 1)] + sbuf[4 + ((g << 1) | 1)];
  } else {
    const int t = 2 * (b - BB / 2) + g;
    if (lid == 0) Mkey[t] = 0u;  // < fkey of any finite float
    float4 x = ((const float4*)(tmean + (size_t)t * DD))[lid];
    float4 l = ((const float4*)(tls + (size_t)t * DD))[lid];
    float ss = x.x * x.x + x.y * x.y + x.z * x.z + x.w * x.w;
    ss = wave_reduce_sum(ss);
    if ((tid & 63) == 0) sbuf[(g << 1) | wv] = ss;
    __syncthreads();
    ss = sbuf[g << 1] + sbuf[(g << 1) | 1];
    float inv = 1.0f / fmaxf(sqrtf(ss), 1e-12f);
    float tm0 = x.x * inv, tm1 = x.y * inv, tm2 = x.z * inv, tm3 = x.w * inv;
    float sg0 = expf(l.x), sg1 = expf(l.y), sg2 = expf(l.z), sg3 = expf(l.w);
    float se0 = 0.f, se1 = 0.f, se2 = 0.f, se3 = 0.f;
    float sq0 = 0.f, sq1 = 0.f, sq2 = 0.f, sq3 = 0.f;
    const float4* ep = (const float4*)(eps + (size_t)t * NS * DD);
#pragma unroll
    for (int s = 0; s < NS; ++s) {
      float4 e = ep[s * (DD / 4) + lid];
      se0 += e.x; sq0 += e.x * e.x;
      se1 += e.y; sq1 += e.y * e.y;
      se2 += e.z; sq2 += e.z * e.z;
      se3 += e.w; sq3 += e.w * e.w;
    }
    const float i7 = 1.0f / 7.0f;
    float m0 = sg0 * se0 * i7, m1 = sg1 * se1 * i7;
    float m2 = sg2 * se2 * i7, m3 = sg3 * se3 * i7;
    unsigned short* brow = Bcat + (size_t)t * KK;
    ushort4 s2p, s1p;
    s2p.x = f2bf(tm0 * tm0 + 2.0f * tm0 * m0 + sg0 * sg0 * sq0 * i7);
    s2p.y = f2bf(tm1 * tm1 + 2.0f * tm1 * m1 + sg1 * sg1 * sq1 * i7);
    s2p.z = f2bf(tm2 * tm2 + 2.0f * tm2 * m2 + sg2 * sg2 * sq2 * i7);
    s2p.w = f2bf(tm3 * tm3 + 2.0f * tm3 * m3 + sg3 * sg3 * sq3 * i7);
    s1p.x = f2bf(tm0 + m0); s1p.y = f2bf(tm1 + m1);
    s1p.z = f2bf(tm2 + m2); s1p.w = f2bf(tm3 + m3);
    *(ushort4*)&brow[swz(t, c0)]      = s2p;
    *(ushort4*)&brow[swz(t, DD + c0)] = s1p;
  }
}

// ---------------------------------------------------------------------------
// Kernel 2 (round-7): 128x128 tile, grid 256 (1 block/CU), 4 waves (2x2),
// each wave a 64x64 sub-tile (acc[4][4]). Triple-buffered LDS (96 KB) via
// global_load_lds dwordx4; counted vmcnt(8) (own tile's 8 loads landed,
// next tile's 8 in flight); setprio around MFMA; XCD 4x8 rectangles
// (A 1MB + B 2MB unique per XCD < 4MB private L2). Staging traffic
// 192MB -> 128MB vs round-6; ds_read per MFMA 0.75 -> 0.5.
__global__ __launch_bounds__(256) void gemm_loc(
    const unsigned short* __restrict__ Acat,
    const unsigned short* __restrict__ Bcat,
    const float* __restrict__ qterm,
    unsigned short* __restrict__ loc, unsigned* __restrict__ Mkey) {
  __shared__ short As[3][BM * BK];  // 3 x 16 KB
  __shared__ short Bs[3][BN * BK];  // 3 x 16 KB
  const int tid = threadIdx.x, lane = tid & 63, wid = tid >> 6;
  const int lin = blockIdx.y * (BB / BN) + blockIdx.x;  // 0..255
  const int xcd = lin & 7, j = lin >> 3;                // dispatch round-robins XCDs
  const int tr = ((xcd >> 1) << 2) + (j >> 3);          // tile row 0..15 (4 per XCD)
  const int tc = ((xcd & 1) << 3) + (j & 7);            // tile col 0..15 (8 per XCD)
  const int brow = tr * BM, bcol = tc * BN;
  const int wr = wid >> 1, wc = wid & 1;                // wave 64x64 sub-tile
  const int fr = lane & 15, kg = lane >> 4, f7 = fr & 7;
  const int srow = lane >> 3, scol = (lane & 7) * 8;

  floatx4 acc[4][4];
#pragma unroll
  for (int m = 0; m < 4; ++m)
#pragma unroll
    for (int n = 0; n < 4; ++n) acc[m][n] = (floatx4){0.f, 0.f, 0.f, 0.f};

  // each wave stages 32 rows of A and 32 rows of B per K-tile (4+4 loads/thread)
  const unsigned short* gA = Acat + (size_t)(brow + wid * 32 + srow) * KK + scol;
  const unsigned short* gB = Bcat + (size_t)(bcol + wid * 32 + srow) * KK + scol;

#define STAGE(buf, kc)                                                        \
  {                                                                           \
    short* la = &As[buf][wid * 2048];                                         \
    short* lb = &Bs[buf][wid * 2048];                                         \
    _Pragma("unroll")                                                         \
    for (int j2 = 0; j2 < 4; ++j2) {                                          \
      gl2lds16(gA + (size_t)j2 * 8 * KK + (kc), la + j2 * 512);               \
      gl2lds16(gB + (size_t)j2 * 8 * KK + (kc), lb + j2 * 512);               \
    }                                                                         \
  }

  // prologue: stage K-tiles 0,1 (16 loads in flight / thread)
  STAGE(0, 0)
  STAGE(1, BK)

#pragma unroll
  for (int kt = 0; kt < NT; ++kt) {
    // own tile-kt's 8 loads landed; tile kt+1's 8 may stay in flight
    if (kt < NT - 1) asm volatile("s_waitcnt vmcnt(8)" ::: "memory");
    else             asm volatile("s_waitcnt vmcnt(0)" ::: "memory");
    __builtin_amdgcn_s_barrier();  // all waves' tile-kt data now in LDS
    if (kt + 2 < NT) {
      // overwrite buf[(kt+2)%3] = buf[(kt-1)%3]: reads finished pre-barrier
      STAGE((kt + 2) % 3, (kt + 2) * BK)
    }
    const short* a  = As[kt % 3];
    const short* bp = Bs[kt % 3];
#pragma unroll
    for (int kh = 0; kh < 2; ++kh) {
      const int co = (((kh * 4 + kg) ^ f7) << 3);  // un-swizzle chunk
      short8 af[4], bf[4];
#pragma unroll
      for (int m = 0; m < 4; ++m)
        af[m] = *reinterpret_cast<const short8*>(&a[(wr * 64 + m * 16 + fr) * BK + co]);
#pragma unroll
      for (int n = 0; n < 4; ++n)
        bf[n] = *reinterpret_cast<const short8*>(&bp[(wc * 64 + n * 16 + fr) * BK + co]);
      __builtin_amdgcn_s_setprio(1);
#pragma unroll
      for (int m = 0; m < 4; ++m)
#pragma unroll
        for (int n = 0; n < 4; ++n)
          acc[m][n] = __builtin_amdgcn_mfma_f32_16x16x32_bf16(af[m], bf[n],
                                                              acc[m][n], 0, 0, 0);
      __builtin_amdgcn_s_setprio(0);
    }
  }
#undef STAGE

  // epilogue: C row = 4*kg + r4 (+m*16 + wr*64), col = fr (+n*16 + wc*64)
#pragma unroll
  for (int n = 0; n < 4; ++n) {
    const int col = bcol + wc * 64 + n * 16 + fr;
    float cm = -3.402823466e38f;
#pragma unroll
    for (int m = 0; m < 4; ++m) {
      const int row = brow + wr * 64 + m * 16 + kg * 4;
#pragma unroll
      for (int r4 = 0; r4 < 4; ++r4) {
        float v = -0.5f * (acc[m][n][r4] + qterm[row + r4]);
        loc[(size_t)(row + r4) * BB + col] = f2bf(v);
        cm = fmaxf(cm, v);
      }
    }
    cm = fmaxf(cm, __shfl_xor(cm, 16, 64));
    cm = fmaxf(cm, __shfl_xor(cm, 32, 64));
    if (kg == 0) atomicMax(&Mkey[col], fkey(cm));  // order-invariant
  }
}

// ---------------------------------------------------------------------------
// Kernel 3: per-row LSE + diag -> rowval[q]. Single pass, all in registers;
// no global atomics (round-2 lesson: same-address atomics serialize brutally).
__global__ __launch_bounds__(256) void row_lse(
    const unsigned short* __restrict__ loc, const unsigned* __restrict__ Mkey,
    float* __restrict__ rowval) {
  __shared__ float sbuf[4];
  __shared__ float sdiag;
  const int q = blockIdx.x, tid = threadIdx.x;
  short8 v = ((const short8*)(loc + (size_t)q * BB))[tid];  // t = 8tid..8tid+7
  uint4 k0 = ((const uint4*)Mkey)[2 * tid];
  uint4 k1 = ((const uint4*)Mkey)[2 * tid + 1];
  float xs[8];
  xs[0] = bf2f((unsigned short)v[0]) - funkey(k0.x);
  xs[1] = bf2f((unsigned short)v[1]) - funkey(k0.y);
  xs[2] = bf2f((unsigned short)v[2]) - funkey(k0.z);
  xs[3] = bf2f((unsigned short)v[3]) - funkey(k0.w);
  xs[4] = bf2f((unsigned short)v[4]) - funkey(k1.x);
  xs[5] = bf2f((unsigned short)v[5]) - funkey(k1.y);
  xs[6] = bf2f((unsigned short)v[6]) - funkey(k1.z);
  xs[7] = bf2f((unsigned short)v[7]) - funkey(k1.w);
  float m = xs[0];
#pragma unroll
  for (int i = 1; i < 8; ++i) m = fmaxf(m, xs[i]);
  if ((q >> 3) == tid) sdiag = xs[q & 7];
  m = block_reduce_max256(m, sbuf);  // contains barriers -> sdiag visible
  float s = 0.f;
#pragma unroll
  for (int i = 0; i < 8; ++i) s += expf(xs[i] - m);
  s = block_reduce_sum256(s, sbuf);
  if (tid == 0) rowval[q] = sdiag - (m + logf(s));
}

// ---------------------------------------------------------------------------
// Kernel 4: loss = -mean_q rowval[q]  (single block)
__global__ __launch_bounds__(256) void final_loss(
    const float* __restrict__ rowval, float* __restrict__ out) {
  __shared__ float sbuf[4];
  const int tid = threadIdx.x;
  float s = 0.f;
#pragma unroll
  for (int i = 0; i < 8; ++i) s += rowval[tid + i * 256];
  s = block_reduce_sum256(s, sbuf);
  if (tid == 0) out[0] = -s * (1.0f / (float)BB);
}

// ---------------------------------------------------------------------------
extern "C" void kernel_launch(void* const* d_in, const int* in_sizes, int n_in,
                              void* d_out, int out_size, void* d_ws, size_t ws_size,
                              hipStream_t stream) {
  const float* qmean = (const float*)d_in[0];
  const float* qls   = (const float*)d_in[1];
  // d_in[2] query_z: cancels (broadcasts on target axis -> drops in colmax+softmax)
  const float* tmean = (const float*)d_in[3];
  const float* tls   = (const float*)d_in[4];
  // d_in[5] target_z: unused by reference
  const float* eps   = (const float*)d_in[6];

  char* ws = (char*)d_ws;
  unsigned short* Acat = (unsigned short*)(ws + 0);                  // 4 MB
  unsigned short* Bcat = (unsigned short*)(ws + (4u << 20));         // 4 MB
  float* qterm         = (float*)(ws + (8u << 20));                  // 8 KB
  unsigned* Mkey       = (unsigned*)(ws + (8u << 20) + 8192);        // 8 KB
  float* rowval        = (float*)(ws + (8u << 20) + 16384);          // 8 KB
  unsigned short* loc  = (unsigned short*)(ws + (8u << 20) + 65536); // 8 MB

  prep<<<BB, 256, 0, stream>>>(qmean, qls, tmean, tls, eps,
                               Acat, Bcat, qterm, Mkey);
  gemm_loc<<<dim3(BB / BN, BB / BM), 256, 0, stream>>>(Acat, Bcat, qterm, loc, Mkey);
  row_lse<<<BB, 256, 0, stream>>>(loc, Mkey, rowval);
  final_loss<<<1, 256, 0, stream>>>(rowval, (float*)d_out);
}

// Round 8
// 37.835 us; speedup vs baseline: 1.0555x; 1.0555x over previous
//
#include <hip/hip_runtime.h>
#include <math.h>

#define BB 2048
#define DD 512
#define NS 7
#define KK 1024   // 2*DD concatenated GEMM K
#define BM 128
#define BN 128
#define BK 64
#define NT (KK / BK)  // 16 K-steps

typedef __attribute__((ext_vector_type(8))) short short8;
typedef __attribute__((ext_vector_type(4))) float floatx4;

typedef const __attribute__((address_space(1))) void gv_t;
typedef __attribute__((address_space(3))) void lv_t;
__device__ __forceinline__ void gl2lds16(const void* g, void* l) {
  __builtin_amdgcn_global_load_lds((gv_t*)g, (lv_t*)l, 16, 0, 0);
}

__device__ __forceinline__ unsigned short f2bf(float f) {
  unsigned int u = __float_as_uint(f);
  u += 0x7FFFu + ((u >> 16) & 1u);  // RNE
  return (unsigned short)(u >> 16);
}
__device__ __forceinline__ float bf2f(unsigned short u) {
  return __uint_as_float(((unsigned)u) << 16);
}

// monotone float<->uint key for atomicMax over signed floats
__device__ __forceinline__ unsigned fkey(float f) {
  unsigned u = __float_as_uint(f);
  return (u & 0x80000000u) ? ~u : (u | 0x80000000u);
}
__device__ __forceinline__ float funkey(unsigned k) {
  unsigned u = (k & 0x80000000u) ? (k ^ 0x80000000u) : ~k;
  return __uint_as_float(u);
}

// chunk-XOR swizzle of the K index within each 64-col group, keyed by row&7.
// Producer (prep) writes swizzled; GEMM's linear global_load_lds staging then
// lands a swizzled LDS tile whose ds_read_b128 frag reads are bank-balanced.
__device__ __forceinline__ int swz(int row, int c) {
  return (c & ~0x38) | ((((c >> 3) ^ row) & 7) << 3);
}

__device__ __forceinline__ float wave_reduce_sum(float v) {
#pragma unroll
  for (int off = 32; off > 0; off >>= 1) v += __shfl_down(v, off, 64);
  return v;
}
__device__ __forceinline__ float wave_reduce_max(float v) {
#pragma unroll
  for (int off = 32; off > 0; off >>= 1) v = fmaxf(v, __shfl_down(v, off, 64));
  return v;
}
__device__ __forceinline__ float block_reduce_sum256(float v, float* sbuf) {
  v = wave_reduce_sum(v);
  if ((threadIdx.x & 63) == 0) sbuf[threadIdx.x >> 6] = v;
  __syncthreads();
  float r = sbuf[0] + sbuf[1] + sbuf[2] + sbuf[3];
  __syncthreads();
  return r;
}
__device__ __forceinline__ float block_reduce_max256(float v, float* sbuf) {
  v = wave_reduce_max(v);
  if ((threadIdx.x & 63) == 0) sbuf[threadIdx.x >> 6] = v;
  __syncthreads();
  float r = fmaxf(fmaxf(sbuf[0], sbuf[1]), fmaxf(sbuf[2], sbuf[3]));
  __syncthreads();
  return r;
}

// ---------------------------------------------------------------------------
// Kernel 1 (merged prep): 16B/lane float4, 2 rows per block.
// Blocks [0,1024): query rows 2b,2b+1.  Blocks [1024,2048): target rows.
// Group g = tid>>7 owns one row with 128 threads (2 waves).
__global__ __launch_bounds__(256) void prep(
    const float* __restrict__ qmean, const float* __restrict__ qls,
    const float* __restrict__ tmean, const float* __restrict__ tls,
    const float* __restrict__ eps,
    unsigned short* __restrict__ Acat, unsigned short* __restrict__ Bcat,
    float* __restrict__ qterm, unsigned* __restrict__ Mkey) {
  __shared__ float sbuf[8];  // [0..3]: reduce round 0, [4..7]: round 1
  const int b = blockIdx.x, tid = threadIdx.x;
  const int g = tid >> 7, lid = tid & 127, wv = (tid >> 6) & 1;
  const int c0 = 4 * lid;
  if (b < BB / 2) {
    const int q = 2 * b + g;
    float4 x = ((const float4*)(qmean + (size_t)q * DD))[lid];
    float4 l = ((const float4*)(qls + (size_t)q * DD))[lid];
    float ss = x.x * x.x + x.y * x.y + x.z * x.z + x.w * x.w;
    ss = wave_reduce_sum(ss);
    if ((tid & 63) == 0) sbuf[(g << 1) | wv] = ss;
    __syncthreads();
    ss = sbuf[g << 1] + sbuf[(g << 1) | 1];
    float inv = 1.0f / fmaxf(sqrtf(ss), 1e-12f);
    float w0 = expf(-l.x), w1 = expf(-l.y), w2 = expf(-l.z), w3 = expf(-l.w);
    float n0 = x.x * inv, n1 = x.y * inv, n2 = x.z * inv, n3 = x.w * inv;
    unsigned short* arow = Acat + (size_t)q * KK;
    ushort4 wp, np;
    wp.x = f2bf(w0); wp.y = f2bf(w1); wp.z = f2bf(w2); wp.w = f2bf(w3);
    np.x = f2bf(-2.0f * n0 * w0); np.y = f2bf(-2.0f * n1 * w1);
    np.z = f2bf(-2.0f * n2 * w2); np.w = f2bf(-2.0f * n3 * w3);
    *(ushort4*)&arow[swz(q, c0)]      = wp;
    *(ushort4*)&arow[swz(q, DD + c0)] = np;
    float qt = n0 * n0 * w0 + n1 * n1 * w1 + n2 * n2 * w2 + n3 * n3 * w3;
    qt = wave_reduce_sum(qt);
    if ((tid & 63) == 0) sbuf[4 + ((g << 1) | wv)] = qt;
    __syncthreads();
    if (lid == 0) qterm[q] = sbuf[4 + (g << 1)] + sbuf[4 + ((g << 1) | 1)];
  } else {
    const int t = 2 * (b - BB / 2) + g;
    if (lid == 0) Mkey[t] = 0u;  // < fkey of any finite float
    float4 x = ((const float4*)(tmean + (size_t)t * DD))[lid];
    float4 l = ((const float4*)(tls + (size_t)t * DD))[lid];
    float ss = x.x * x.x + x.y * x.y + x.z * x.z + x.w * x.w;
    ss = wave_reduce_sum(ss);
    if ((tid & 63) == 0) sbuf[(g << 1) | wv] = ss;
    __syncthreads();
    ss = sbuf[g << 1] + sbuf[(g << 1) | 1];
    float inv = 1.0f / fmaxf(sqrtf(ss), 1e-12f);
    float tm0 = x.x * inv, tm1 = x.y * inv, tm2 = x.z * inv, tm3 = x.w * inv;
    float sg0 = expf(l.x), sg1 = expf(l.y), sg2 = expf(l.z), sg3 = expf(l.w);
    float se0 = 0.f, se1 = 0.f, se2 = 0.f, se3 = 0.f;
    float sq0 = 0.f, sq1 = 0.f, sq2 = 0.f, sq3 = 0.f;
    const float4* ep = (const float4*)(eps + (size_t)t * NS * DD);
#pragma unroll
    for (int s = 0; s < NS; ++s) {
      float4 e = ep[s * (DD / 4) + lid];
      se0 += e.x; sq0 += e.x * e.x;
      se1 += e.y; sq1 += e.y * e.y;
      se2 += e.z; sq2 += e.z * e.z;
      se3 += e.w; sq3 += e.w * e.w;
    }
    const float i7 = 1.0f / 7.0f;
    float m0 = sg0 * se0 * i7, m1 = sg1 * se1 * i7;
    float m2 = sg2 * se2 * i7, m3 = sg3 * se3 * i7;
    unsigned short* brow = Bcat + (size_t)t * KK;
    ushort4 s2p, s1p;
    s2p.x = f2bf(tm0 * tm0 + 2.0f * tm0 * m0 + sg0 * sg0 * sq0 * i7);
    s2p.y = f2bf(tm1 * tm1 + 2.0f * tm1 * m1 + sg1 * sg1 * sq1 * i7);
    s2p.z = f2bf(tm2 * tm2 + 2.0f * tm2 * m2 + sg2 * sg2 * sq2 * i7);
    s2p.w = f2bf(tm3 * tm3 + 2.0f * tm3 * m3 + sg3 * sg3 * sq3 * i7);
    s1p.x = f2bf(tm0 + m0); s1p.y = f2bf(tm1 + m1);
    s1p.z = f2bf(tm2 + m2); s1p.w = f2bf(tm3 + m3);
    *(ushort4*)&brow[swz(t, c0)]      = s2p;
    *(ushort4*)&brow[swz(t, DD + c0)] = s1p;
  }
}

// ---------------------------------------------------------------------------
// Kernel 2 (round-8): 128x128 tile, 512 threads = 8 waves (2x4), grid 256
// (1 block/CU, 8 waves/CU = 2/SIMD like round 6). Each wave owns 64x32
// (acc[4][2]). Triple-buffered LDS (96 KB) via global_load_lds dwordx4;
// counted vmcnt(4) (own tile's 4 loads landed, next tile's in flight);
// setprio around MFMA; XCD 4x8 rectangles (A 1MB + B 2MB < 4MB L2).
// Staging traffic 128MB (vs 192MB for BN=64).
__global__ __launch_bounds__(512) void gemm_loc(
    const unsigned short* __restrict__ Acat,
    const unsigned short* __restrict__ Bcat,
    const float* __restrict__ qterm,
    unsigned short* __restrict__ loc, unsigned* __restrict__ Mkey) {
  __shared__ short As[3][BM * BK];  // 3 x 16 KB
  __shared__ short Bs[3][BN * BK];  // 3 x 16 KB
  const int tid = threadIdx.x, lane = tid & 63, wid = tid >> 6;  // wid 0..7
  const int lin = blockIdx.x;                           // 0..255
  const int xcd = lin & 7, j = lin >> 3;                // dispatch round-robins XCDs
  const int tr = ((xcd >> 1) << 2) + (j >> 3);          // tile row 0..15 (4 per XCD)
  const int tc = ((xcd & 1) << 3) + (j & 7);            // tile col 0..15 (8 per XCD)
  const int brow = tr * BM, bcol = tc * BN;
  const int wr = wid >> 2, wc = wid & 3;                // wave 64x32 sub-tile
  const int fr = lane & 15, kg = lane >> 4, f7 = fr & 7;
  const int srow = lane >> 3, scol = (lane & 7) * 8;

  floatx4 acc[4][2];
#pragma unroll
  for (int m = 0; m < 4; ++m)
#pragma unroll
    for (int n = 0; n < 2; ++n) acc[m][n] = (floatx4){0.f, 0.f, 0.f, 0.f};

  // each wave stages 16 rows of A and 16 rows of B per K-tile (2+2 loads/thread)
  const unsigned short* gA = Acat + (size_t)(brow + wid * 16 + srow) * KK + scol;
  const unsigned short* gB = Bcat + (size_t)(bcol + wid * 16 + srow) * KK + scol;

#define STAGE(buf, kc)                                                        \
  {                                                                           \
    short* la = &As[buf][wid * 1024];                                         \
    short* lb = &Bs[buf][wid * 1024];                                         \
    _Pragma("unroll")                                                         \
    for (int j2 = 0; j2 < 2; ++j2) {                                          \
      gl2lds16(gA + (size_t)j2 * 8 * KK + (kc), la + j2 * 512);               \
      gl2lds16(gB + (size_t)j2 * 8 * KK + (kc), lb + j2 * 512);               \
    }                                                                         \
  }

  // prologue: stage K-tiles 0,1 (8 loads in flight / thread)
  STAGE(0, 0)
  STAGE(1, BK)

#pragma unroll
  for (int kt = 0; kt < NT; ++kt) {
    // own tile-kt's 4 loads landed; tile kt+1's 4 may stay in flight
    if (kt < NT - 1) asm volatile("s_waitcnt vmcnt(4)" ::: "memory");
    else             asm volatile("s_waitcnt vmcnt(0)" ::: "memory");
    __builtin_amdgcn_s_barrier();  // all waves' tile-kt data now in LDS
    if (kt + 2 < NT) {
      // overwrite buf[(kt+2)%3] = buf[(kt-1)%3]: reads finished pre-barrier
      STAGE((kt + 2) % 3, (kt + 2) * BK)
    }
    const short* a  = As[kt % 3];
    const short* bp = Bs[kt % 3];
#pragma unroll
    for (int kh = 0; kh < 2; ++kh) {
      const int co = (((kh * 4 + kg) ^ f7) << 3);  // un-swizzle chunk
      short8 af[4], bf[2];
#pragma unroll
      for (int m = 0; m < 4; ++m)
        af[m] = *reinterpret_cast<const short8*>(&a[(wr * 64 + m * 16 + fr) * BK + co]);
#pragma unroll
      for (int n = 0; n < 2; ++n)
        bf[n] = *reinterpret_cast<const short8*>(&bp[(wc * 32 + n * 16 + fr) * BK + co]);
      __builtin_amdgcn_s_setprio(1);
#pragma unroll
      for (int m = 0; m < 4; ++m)
#pragma unroll
        for (int n = 0; n < 2; ++n)
          acc[m][n] = __builtin_amdgcn_mfma_f32_16x16x32_bf16(af[m], bf[n],
                                                              acc[m][n], 0, 0, 0);
      __builtin_amdgcn_s_setprio(0);
    }
  }
#undef STAGE

  // epilogue: C row = 4*kg + r4 (+m*16 + wr*64), col = fr (+n*16 + wc*32)
#pragma unroll
  for (int n = 0; n < 2; ++n) {
    const int col = bcol + wc * 32 + n * 16 + fr;
    float cm = -3.402823466e38f;
#pragma unroll
    for (int m = 0; m < 4; ++m) {
      const int row = brow + wr * 64 + m * 16 + kg * 4;
#pragma unroll
      for (int r4 = 0; r4 < 4; ++r4) {
        float v = -0.5f * (acc[m][n][r4] + qterm[row + r4]);
        loc[(size_t)(row + r4) * BB + col] = f2bf(v);
        cm = fmaxf(cm, v);
      }
    }
    cm = fmaxf(cm, __shfl_xor(cm, 16, 64));
    cm = fmaxf(cm, __shfl_xor(cm, 32, 64));
    if (kg == 0) atomicMax(&Mkey[col], fkey(cm));  // order-invariant
  }
}

// ---------------------------------------------------------------------------
// Kernel 3: per-row LSE + diag -> rowval[q]. Single pass, all in registers;
// no global atomics (round-2 lesson: same-address atomics serialize brutally).
__global__ __launch_bounds__(256) void row_lse(
    const unsigned short* __restrict__ loc, const unsigned* __restrict__ Mkey,
    float* __restrict__ rowval) {
  __shared__ float sbuf[4];
  __shared__ float sdiag;
  const int q = blockIdx.x, tid = threadIdx.x;
  short8 v = ((const short8*)(loc + (size_t)q * BB))[tid];  // t = 8tid..8tid+7
  uint4 k0 = ((const uint4*)Mkey)[2 * tid];
  uint4 k1 = ((const uint4*)Mkey)[2 * tid + 1];
  float xs[8];
  xs[0] = bf2f((unsigned short)v[0]) - funkey(k0.x);
  xs[1] = bf2f((unsigned short)v[1]) - funkey(k0.y);
  xs[2] = bf2f((unsigned short)v[2]) - funkey(k0.z);
  xs[3] = bf2f((unsigned short)v[3]) - funkey(k0.w);
  xs[4] = bf2f((unsigned short)v[4]) - funkey(k1.x);
  xs[5] = bf2f((unsigned short)v[5]) - funkey(k1.y);
  xs[6] = bf2f((unsigned short)v[6]) - funkey(k1.z);
  xs[7] = bf2f((unsigned short)v[7]) - funkey(k1.w);
  float m = xs[0];
#pragma unroll
  for (int i = 1; i < 8; ++i) m = fmaxf(m, xs[i]);
  if ((q >> 3) == tid) sdiag = xs[q & 7];
  m = block_reduce_max256(m, sbuf);  // contains barriers -> sdiag visible
  float s = 0.f;
#pragma unroll
  for (int i = 0; i < 8; ++i) s += expf(xs[i] - m);
  s = block_reduce_sum256(s, sbuf);
  if (tid == 0) rowval[q] = sdiag - (m + logf(s));
}

// ---------------------------------------------------------------------------
// Kernel 4: loss = -mean_q rowval[q]  (single block)
__global__ __launch_bounds__(256) void final_loss(
    const float* __restrict__ rowval, float* __restrict__ out) {
  __shared__ float sbuf[4];
  const int tid = threadIdx.x;
  float s = 0.f;
#pragma unroll
  for (int i = 0; i < 8; ++i) s += rowval[tid + i * 256];
  s = block_reduce_sum256(s, sbuf);
  if (tid == 0) out[0] = -s * (1.0f / (float)BB);
}

// ---------------------------------------------------------------------------
extern "C" void kernel_launch(void* const* d_in, const int* in_sizes, int n_in,
                              void* d_out, int out_size, void* d_ws, size_t ws_size,
                              hipStream_t stream) {
  const float* qmean = (const float*)d_in[0];
  const float* qls   = (const float*)d_in[1];
  // d_in[2] query_z: cancels (broadcasts on target axis -> drops in colmax+softmax)
  const float* tmean = (const float*)d_in[3];
  const float* tls   = (const float*)d_in[4];
  // d_in[5] target_z: unused by reference
  const float* eps   = (const float*)d_in[6];

  char* ws = (char*)d_ws;
  unsigned short* Acat = (unsigned short*)(ws + 0);                  // 4 MB
  unsigned short* Bcat = (unsigned short*)(ws + (4u << 20));         // 4 MB
  float* qterm         = (float*)(ws + (8u << 20));                  // 8 KB
  unsigned* Mkey       = (unsigned*)(ws + (8u << 20) + 8192);        // 8 KB
  float* rowval        = (float*)(ws + (8u << 20) + 16384);          // 8 KB
  unsigned short* loc  = (unsigned short*)(ws + (8u << 20) + 65536); // 8 MB

  prep<<<BB, 256, 0, stream>>>(qmean, qls, tmean, tls, eps,
                               Acat, Bcat, qterm, Mkey);
  gemm_loc<<<(BB / BM) * (BB / BN), 512, 0, stream>>>(Acat, Bcat, qterm, loc, Mkey);
  row_lse<<<BB, 256, 0, stream>>>(loc, Mkey, rowval);
  final_loss<<<1, 256, 0, stream>>>(rowval, (float*)d_out);
}

// Round 9
// 34.928 us; speedup vs baseline: 1.1434x; 1.0832x over previous
//
#include <hip/hip_runtime.h>
#include <math.h>

#define BB 2048
#define DD 512
#define NS 7
#define KK 1024   // GEMM K (elements == bytes in fp8)
#define BM 128
#define BN 64
#define BK 64     // K-elements (= bytes) per tile
#define NT (KK / BK)  // 16 K-steps

typedef __attribute__((ext_vector_type(8))) short short8;
typedef __attribute__((ext_vector_type(4))) float floatx4;
typedef long long i64;

typedef const __attribute__((address_space(1))) void gv_t;
typedef __attribute__((address_space(3))) void lv_t;
__device__ __forceinline__ void gl2lds16(const void* g, void* l) {
  __builtin_amdgcn_global_load_lds((gv_t*)g, (lv_t*)l, 16, 0, 0);
}

__device__ __forceinline__ unsigned short f2bf(float f) {
  unsigned int u = __float_as_uint(f);
  u += 0x7FFFu + ((u >> 16) & 1u);  // RNE
  return (unsigned short)(u >> 16);
}
__device__ __forceinline__ float bf2f(unsigned short u) {
  return __uint_as_float(((unsigned)u) << 16);
}

// monotone float<->uint key for atomicMax over signed floats
__device__ __forceinline__ unsigned fkey(float f) {
  unsigned u = __float_as_uint(f);
  return (u & 0x80000000u) ? ~u : (u | 0x80000000u);
}
__device__ __forceinline__ float funkey(unsigned k) {
  unsigned u = (k & 0x80000000u) ? (k ^ 0x80000000u) : ~k;
  return __uint_as_float(u);
}

// 8 floats -> 8 fp8 e4m3 (OCP, RNE via v_cvt_pk_fp8_f32)
__device__ __forceinline__ uint2 pack8_fp8(const float* v) {
  int lo = 0, hi = 0;
  lo = __builtin_amdgcn_cvt_pk_fp8_f32(v[0], v[1], lo, false);
  lo = __builtin_amdgcn_cvt_pk_fp8_f32(v[2], v[3], lo, true);
  hi = __builtin_amdgcn_cvt_pk_fp8_f32(v[4], v[5], hi, false);
  hi = __builtin_amdgcn_cvt_pk_fp8_f32(v[6], v[7], hi, true);
  uint2 r; r.x = (unsigned)lo; r.y = (unsigned)hi; return r;
}

// Swizzle (fp8): within each 64B K-group of a row, XOR the 16B-chunk index
// (2 bits) with row&3 and the 8B-half bit with (row>>2)&1. Producer writes
// this physical layout to global; GEMM's linear global_load_lds preserves it;
// fragment ds_read_b64 un-swizzles. Conflict analysis: only 2-way aliasing
// (free, m136); b64 wave64 hits the 4-claims/bank floor.

__device__ __forceinline__ float wsum(float v) {
#pragma unroll
  for (int off = 32; off > 0; off >>= 1) v += __shfl_xor(v, off, 64);
  return v;
}
__device__ __forceinline__ float wmax(float v) {
#pragma unroll
  for (int off = 32; off > 0; off >>= 1) v = fmaxf(v, __shfl_xor(v, off, 64));
  return v;
}
__device__ __forceinline__ float block_reduce_sum256(float v, float* sbuf) {
  v = wsum(v);
  if ((threadIdx.x & 63) == 0) sbuf[threadIdx.x >> 6] = v;
  __syncthreads();
  float r = sbuf[0] + sbuf[1] + sbuf[2] + sbuf[3];
  __syncthreads();
  return r;
}

// ---------------------------------------------------------------------------
// Kernel 1: wave-per-row prep (no barriers). 1024 blocks x 4 waves.
// Rows [0,2048) = query q; [2048,4096) = target t.
// A[q][k]: k<512 -> W=exp(-qls); k>=512 -> -2*qm_n*W.   (fp8, swizzled)
// B[t][k]: k<512 -> S2*(1/256);  k>=512 -> S1.          (fp8, swizzled)
__global__ __launch_bounds__(256) void prep(
    const float* __restrict__ qmean, const float* __restrict__ qls,
    const float* __restrict__ tmean, const float* __restrict__ tls,
    const float* __restrict__ eps,
    unsigned char* __restrict__ Acat, unsigned char* __restrict__ Bcat,
    float* __restrict__ qterm, unsigned* __restrict__ Mkey) {
  const int w = threadIdx.x >> 6, lane = threadIdx.x & 63;
  const int r = blockIdx.x * 4 + w;  // 0..4095
  // swizzled in-group byte offset for this lane's 8 consecutive elements
  const int grp = (lane >> 3) * 64;
  const int physoff = (((((lane & 7) >> 1) ^ r) & 3) << 4) |
                      ((((lane & 7) ^ (r >> 2)) & 1) << 3);
  if (r < BB) {
    const int q = r;
    const float4* xm = (const float4*)(qmean + (size_t)q * DD);
    const float4* xl = (const float4*)(qls + (size_t)q * DD);
    float4 a0 = xm[2 * lane], a1 = xm[2 * lane + 1];
    float4 l0 = xl[2 * lane], l1 = xl[2 * lane + 1];
    float x[8] = {a0.x, a0.y, a0.z, a0.w, a1.x, a1.y, a1.z, a1.w};
    float l[8] = {l0.x, l0.y, l0.z, l0.w, l1.x, l1.y, l1.z, l1.w};
    float ss = 0.f;
#pragma unroll
    for (int e = 0; e < 8; ++e) ss += x[e] * x[e];
    ss = wsum(ss);
    float inv = 1.0f / fmaxf(sqrtf(ss), 1e-12f);
    float W[8], M2[8], qt = 0.f;
#pragma unroll
    for (int e = 0; e < 8; ++e) {
      W[e] = expf(-l[e]);
      float n = x[e] * inv;
      M2[e] = -2.0f * n * W[e];
      qt += n * n * W[e];
    }
    qt = wsum(qt);
    if (lane == 0) qterm[q] = qt;
    unsigned char* arow = Acat + (size_t)q * KK;
    *(uint2*)(arow + grp + physoff)       = pack8_fp8(W);
    *(uint2*)(arow + 512 + grp + physoff) = pack8_fp8(M2);
  } else {
    const int t = r - BB;
    if (lane == 0) Mkey[t] = 0u;  // < fkey of any finite float
    const float4* xm = (const float4*)(tmean + (size_t)t * DD);
    const float4* xl = (const float4*)(tls + (size_t)t * DD);
    float4 a0 = xm[2 * lane], a1 = xm[2 * lane + 1];
    float4 l0 = xl[2 * lane], l1 = xl[2 * lane + 1];
    float x[8] = {a0.x, a0.y, a0.z, a0.w, a1.x, a1.y, a1.z, a1.w};
    float l[8] = {l0.x, l0.y, l0.z, l0.w, l1.x, l1.y, l1.z, l1.w};
    float ss = 0.f;
#pragma unroll
    for (int e = 0; e < 8; ++e) ss += x[e] * x[e];
    ss = wsum(ss);
    float inv = 1.0f / fmaxf(sqrtf(ss), 1e-12f);
    float se[8], sq[8];
#pragma unroll
    for (int e = 0; e < 8; ++e) { se[e] = 0.f; sq[e] = 0.f; }
    const float4* ep = (const float4*)(eps + (size_t)t * NS * DD);
#pragma unroll
    for (int s = 0; s < NS; ++s) {
      float4 e0 = ep[s * (DD / 4) + 2 * lane];
      float4 e1 = ep[s * (DD / 4) + 2 * lane + 1];
      float ev[8] = {e0.x, e0.y, e0.z, e0.w, e1.x, e1.y, e1.z, e1.w};
#pragma unroll
      for (int e = 0; e < 8; ++e) { se[e] += ev[e]; sq[e] += ev[e] * ev[e]; }
    }
    const float i7 = 1.0f / 7.0f;
    float S2[8], S1[8];
#pragma unroll
    for (int e = 0; e < 8; ++e) {
      float tm = x[e] * inv;
      float sg = expf(l[e]);
      float m1 = sg * se[e] * i7;
      S1[e] = tm + m1;
      S2[e] = (tm * tm + 2.0f * tm * m1 + sg * sg * sq[e] * i7) * 0.00390625f;  // /256
    }
    unsigned char* brow = Bcat + (size_t)t * KK;
    *(uint2*)(brow + grp + physoff)       = pack8_fp8(S2);
    *(uint2*)(brow + 512 + grp + physoff) = pack8_fp8(S1);
  }
}

// ---------------------------------------------------------------------------
// Kernel 2 (round-9): fp8 GEMM, round-6 structure. 128x64 tile, 4 waves,
// grid 512 (2 blocks/CU), triple-buffered LDS (36 KB) via global_load_lds;
// counted vmcnt(3); setprio; 2-level XCD 8x8 rectangles. Split accumulators:
// kt<8 (S2-half, scale 256) vs kt>=8 (S1-half, scale 1).
__global__ __launch_bounds__(256) void gemm_loc(
    const unsigned char* __restrict__ Acat,
    const unsigned char* __restrict__ Bcat,
    const float* __restrict__ qterm,
    unsigned short* __restrict__ loc, unsigned* __restrict__ Mkey) {
  __shared__ __align__(16) char As[3][BM * BK];  // 3 x 8 KB
  __shared__ __align__(16) char Bs[3][BN * BK];  // 3 x 4 KB
  const int tid = threadIdx.x, lane = tid & 63, wid = tid >> 6;
  const int lin = blockIdx.y * (BB / BN) + blockIdx.x;  // 0..511
  const int xcd = lin & 7, j = lin >> 3;
  const int tr = ((xcd >> 2) << 3) + (j >> 3);          // tile row 0..15
  const int tc = ((xcd & 3) << 3) + (j & 7);            // tile col 0..31
  const int brow = tr * BM, bcol = tc * BN;
  const int wr = wid >> 1, wc = wid & 1;                // wave 64x32 sub-tile
  const int fr = lane & 15, kg = lane >> 4;

  floatx4 acc[2][4][2];
#pragma unroll
  for (int h = 0; h < 2; ++h)
#pragma unroll
    for (int m = 0; m < 4; ++m)
#pragma unroll
      for (int n = 0; n < 2; ++n) acc[h][m][n] = (floatx4){0.f, 0.f, 0.f, 0.f};

  // staging: A chunks tid & tid+256 (rows 0..63, 64..127), B chunk tid (rows 0..63)
  const unsigned char* gA0 = Acat + (size_t)(brow + (tid >> 2)) * KK + (tid & 3) * 16;
  const unsigned char* gA1 = gA0 + (size_t)64 * KK;
  const unsigned char* gB0 = Bcat + (size_t)(bcol + (tid >> 2)) * KK + (tid & 3) * 16;

#define STAGE(buf, kc)                                      \
  {                                                         \
    gl2lds16(gA0 + (kc), &As[buf][tid * 16]);               \
    gl2lds16(gA1 + (kc), &As[buf][4096 + tid * 16]);        \
    gl2lds16(gB0 + (kc), &Bs[buf][tid * 16]);               \
  }

  STAGE(0, 0)
  STAGE(1, BK)

#pragma unroll
  for (int kt = 0; kt < NT; ++kt) {
    if (kt < NT - 1) asm volatile("s_waitcnt vmcnt(3)" ::: "memory");
    else             asm volatile("s_waitcnt vmcnt(0)" ::: "memory");
    __builtin_amdgcn_s_barrier();
    if (kt + 2 < NT) { STAGE((kt + 2) % 3, (kt + 2) * BK) }
    const char* a  = As[kt % 3];
    const char* bp = Bs[kt % 3];
#pragma unroll
    for (int kh = 0; kh < 2; ++kh) {
      // un-swizzle: 16B-chunk = (kh*2 + kg/2) ^ (row&3) == ^ (fr&3);
      // 8B-half = (kg&1) ^ ((row>>2)&1) == ^ ((fr>>2)&1)
      const int co = ((((kh * 2 + (kg >> 1)) ^ fr) & 3) << 4) |
                     (((kg ^ (fr >> 2)) & 1) << 3);
      i64 af[4], bf[2];
#pragma unroll
      for (int m = 0; m < 4; ++m)
        af[m] = *(const i64*)(a + (wr * 64 + m * 16 + fr) * BK + co);
#pragma unroll
      for (int n = 0; n < 2; ++n)
        bf[n] = *(const i64*)(bp + (wc * 32 + n * 16 + fr) * BK + co);
      __builtin_amdgcn_s_setprio(1);
#pragma unroll
      for (int m = 0; m < 4; ++m)
#pragma unroll
        for (int n = 0; n < 2; ++n)
          acc[kt >> 3][m][n] = __builtin_amdgcn_mfma_f32_16x16x32_fp8_fp8(
              af[m], bf[n], acc[kt >> 3][m][n], 0, 0, 0);
      __builtin_amdgcn_s_setprio(0);
    }
  }
#undef STAGE

  // epilogue: recombine halves (S2 was stored /256), fuse column max
#pragma unroll
  for (int n = 0; n < 2; ++n) {
    const int col = bcol + wc * 32 + n * 16 + fr;
    float cm = -3.402823466e38f;
#pragma unroll
    for (int m = 0; m < 4; ++m) {
      const int row = brow + wr * 64 + m * 16 + kg * 4;
#pragma unroll
      for (int r4 = 0; r4 < 4; ++r4) {
        float v = -0.5f * (256.0f * acc[0][m][n][r4] + acc[1][m][n][r4] +
                           qterm[row + r4]);
        loc[(size_t)(row + r4) * BB + col] = f2bf(v);
        cm = fmaxf(cm, v);
      }
    }
    cm = fmaxf(cm, __shfl_xor(cm, 16, 64));
    cm = fmaxf(cm, __shfl_xor(cm, 32, 64));
    if (kg == 0) atomicMax(&Mkey[col], fkey(cm));  // order-invariant
  }
}

// ---------------------------------------------------------------------------
// Kernel 3: wave-per-row LSE + diag (barrier-free). 512 blocks x 4 waves.
__global__ __launch_bounds__(256) void row_lse(
    const unsigned short* __restrict__ loc, const unsigned* __restrict__ Mkey,
    float* __restrict__ rowval) {
  const int w = threadIdx.x >> 6, lane = threadIdx.x & 63;
  const int q = blockIdx.x * 4 + w;
  const short8* lp = (const short8*)(loc + (size_t)q * BB);
  const uint4* kp = (const uint4*)Mkey;
  float xs[4][8];
  float m = -3.402823466e38f, dv = 0.f;
#pragma unroll
  for (int c = 0; c < 4; ++c) {
    short8 v = lp[c * 64 + lane];
    uint4 k0 = kp[(c * 64 + lane) * 2];
    uint4 k1 = kp[(c * 64 + lane) * 2 + 1];
    unsigned ks[8] = {k0.x, k0.y, k0.z, k0.w, k1.x, k1.y, k1.z, k1.w};
#pragma unroll
    for (int e = 0; e < 8; ++e) {
      float x = bf2f((unsigned short)v[e]) - funkey(ks[e]);
      xs[c][e] = x;
      m = fmaxf(m, x);
      if (c * 512 + lane * 8 + e == q) dv = x;  // diag (static idx, cndmask)
    }
  }
  m = wmax(m);
  float s = 0.f;
#pragma unroll
  for (int c = 0; c < 4; ++c)
#pragma unroll
    for (int e = 0; e < 8; ++e) s += expf(xs[c][e] - m);
  s = wsum(s);
  float d = __shfl(dv, (q >> 3) & 63, 64);  // diag lives on lane (q>>3)&63
  if (lane == 0) rowval[q] = d - (m + logf(s));
}

// ---------------------------------------------------------------------------
// Kernel 4: loss = -mean_q rowval[q]  (single block)
__global__ __launch_bounds__(256) void final_loss(
    const float* __restrict__ rowval, float* __restrict__ out) {
  __shared__ float sbuf[4];
  const int tid = threadIdx.x;
  float s = 0.f;
#pragma unroll
  for (int i = 0; i < 8; ++i) s += rowval[tid + i * 256];
  s = block_reduce_sum256(s, sbuf);
  if (tid == 0) out[0] = -s * (1.0f / (float)BB);
}

// ---------------------------------------------------------------------------
extern "C" void kernel_launch(void* const* d_in, const int* in_sizes, int n_in,
                              void* d_out, int out_size, void* d_ws, size_t ws_size,
                              hipStream_t stream) {
  const float* qmean = (const float*)d_in[0];
  const float* qls   = (const float*)d_in[1];
  // d_in[2] query_z: cancels (broadcasts on target axis -> drops in colmax+softmax)
  const float* tmean = (const float*)d_in[3];
  const float* tls   = (const float*)d_in[4];
  // d_in[5] target_z: unused by reference
  const float* eps   = (const float*)d_in[6];

  char* ws = (char*)d_ws;
  unsigned char* Acat  = (unsigned char*)(ws + 0);                   // 2 MB
  unsigned char* Bcat  = (unsigned char*)(ws + (2u << 20));          // 2 MB
  float* qterm         = (float*)(ws + (4u << 20));                  // 8 KB
  unsigned* Mkey       = (unsigned*)(ws + (4u << 20) + 8192);        // 8 KB
  float* rowval        = (float*)(ws + (4u << 20) + 16384);          // 8 KB
  unsigned short* loc  = (unsigned short*)(ws + (4u << 20) + 65536); // 8 MB

  prep<<<1024, 256, 0, stream>>>(qmean, qls, tmean, tls, eps,
                                 Acat, Bcat, qterm, Mkey);
  gemm_loc<<<dim3(BB / BN, BB / BM), 256, 0, stream>>>(Acat, Bcat, qterm, loc, Mkey);
  row_lse<<<512, 256, 0, stream>>>(loc, Mkey, rowval);
  final_loss<<<1, 256, 0, stream>>>(rowval, (float*)d_out);
}